// Round 6
// baseline (718.415 us; speedup 1.0000x reference)
//
#include <hip/hip_runtime.h>

typedef unsigned short u16;
typedef __bf16  bf16x8 __attribute__((ext_vector_type(8)));
typedef float   f32x4  __attribute__((ext_vector_type(4)));
typedef unsigned short us8 __attribute__((ext_vector_type(8)));
typedef _Float16 f16x8 __attribute__((ext_vector_type(8)));
typedef float   fl4   __attribute__((ext_vector_type(4)));

#define AS1 __attribute__((address_space(1)))
#define AS3 __attribute__((address_space(3)))

__device__ __forceinline__ u16 f2bf(float f) {
    union { float f; unsigned u; } x; x.f = f;
    unsigned r = x.u + 0x7fffu + ((x.u >> 16) & 1u);
    return (u16)(r >> 16);
}

// ---------------- fp32 -> bf16 cast, vectorized ----------------
__global__ __launch_bounds__(256) void cvt_f32_bf16(const float* __restrict__ in,
                                                    u16* __restrict__ out, int n8) {
    int i = blockIdx.x * blockDim.x + threadIdx.x;
    int stride = gridDim.x * blockDim.x;
    for (; i < n8; i += stride) {
        const fl4* p = (const fl4*)(in + (long)i * 8);
        fl4 a = p[0], b = p[1];
        us8 o;
#pragma unroll
        for (int j = 0; j < 4; ++j) { o[j] = f2bf(a[j]); o[4 + j] = f2bf(b[j]); }
        *(us8*)(out + (long)i * 8) = o;
    }
}

// ---------------- 128x128 tile bf16 GEMM, C = A * B^T ----------------
// 3-buffer pipeline, within-wave overlap:
//   tile T: stage T+3 -> buf[T%3]; ds_read frags(T+1) <- buf[(T+1)%3] into
//   the spare reg set; MFMA frags(T) with NO mid-tile waits (ds & matrix
//   pipes overlap inside one wave). Boundary: lgkmcnt(0)+vmcnt(8|0)+s_barrier
//   in ONE asm (memory clobber) + sched_barrier(0). Frag sets are NAMED and
//   the loop is unrolled 2x (no runtime-indexed reg arrays).
// Race-freedom (per-wave FIFO vmcnt): boundary T drains exactly stage T+2
// (read next tile), leaves stage T+3 (targets buffer nobody reads/reads-done).
// MODE 0: bf16 out + bias[col]; MODE 1: bf16 out + bias[row];
// MODE 2: fp16 out * scale;     MODE 3: fp32 out.
template <int MODE>
__global__ __launch_bounds__(256, 1) void gemm128p(const u16* __restrict__ A,
                                                   const u16* __restrict__ B,
                                                   void* __restrict__ Cout,
                                                   const float* __restrict__ bias,
                                                   float scale, int K,
                                                   int lda, int ldb, int ldc,
                                                   long sAz, long sBz, long sCz) {
    // per buffer: A 128x64 bf16 = 16 KB, B 128x64 bf16 = 16 KB -> 32 KB; x3 = 96 KiB
    __shared__ alignas(16) char lds8[3 * 32768];

    const int t    = threadIdx.x;
    const int lane = t & 63;
    const int wid  = t >> 6;      // 0..3
    const int wr   = wid >> 1;    // 0..1
    const int wc   = wid & 1;     // 0..1
    const int fr   = lane & 15;
    const int kq   = lane >> 4;

    // XCD-bijective block swizzle (nwg % 8 == 0 for all our launches)
    const int gx  = gridDim.x;
    const int nwg = gx * gridDim.y;
    const int wg  = blockIdx.y * gx + blockIdx.x;
    const int swz = (wg & 7) * (nwg >> 3) + (wg >> 3);
    const long brow = (long)(swz / gx) * 128;
    const long bcol = (long)(swz % gx) * 128;

    const u16* Az = A + sAz * blockIdx.z;
    const u16* Bz = B + sBz * blockIdx.z;

    // staging: dest = r*4096 + t*16 linear; source chunk pre-swizzled (t&7)^(trow&7)
    const int trow = t >> 3;
    const int tc8  = ((t & 7) ^ (trow & 7)) * 8;
    long offA[4], offB[4];
#pragma unroll
    for (int r = 0; r < 4; ++r) offA[r] = (brow + r * 32 + trow) * (long)lda + tc8;
#pragma unroll
    for (int r = 0; r < 4; ++r) offB[r] = (bcol + r * 32 + trow) * (long)ldb + tc8;

    // lane read offsets (swizzled): byte = row*128 + ((ksub*4+kq)^(row&7))*16
    int aRow[4], bRow[4], aCh[2];
#pragma unroll
    for (int m = 0; m < 4; ++m) aRow[m] = (wr * 64 + m * 16 + fr) * 128;
#pragma unroll
    for (int n = 0; n < 4; ++n) bRow[n] = 16384 + (wc * 64 + n * 16 + fr) * 128;
#pragma unroll
    for (int ks = 0; ks < 2; ++ks) aCh[ks] = (((ks << 2) | kq) ^ (fr & 7)) * 16;

    const int NT = K >> 6;        // even, >= 4 for all our shapes
    f32x4 acc[4][4] = {};

    char* b0 = lds8;              // holds tile T   (stage target for T+3)
    char* b1 = lds8 + 32768;      // holds tile T+1 (frag reads)
    char* b2 = lds8 + 65536;      // holds tile T+2

#define STAGE(dst, kcol) do {                                                              \
    _Pragma("unroll")                                                                      \
    for (int r = 0; r < 4; ++r)                                                            \
        __builtin_amdgcn_global_load_lds((const AS1 unsigned*)(Az + offA[r] + (kcol)),     \
                                         (AS3 unsigned*)((dst) + r * 4096 + t * 16), 16, 0, 0); \
    _Pragma("unroll")                                                                      \
    for (int r = 0; r < 4; ++r)                                                            \
        __builtin_amdgcn_global_load_lds((const AS1 unsigned*)(Bz + offB[r] + (kcol)),     \
                                         (AS3 unsigned*)((dst) + 16384 + r * 4096 + t * 16), 16, 0, 0); \
} while (0)

#define READF(FA, FB, bb) do {                                                             \
    _Pragma("unroll")                                                                      \
    for (int ks = 0; ks < 2; ++ks)                                                         \
        _Pragma("unroll")                                                                  \
        for (int m = 0; m < 4; ++m)                                                        \
            FA[ks][m] = *(const bf16x8*)((bb) + aRow[m] + aCh[ks]);                        \
    _Pragma("unroll")                                                                      \
    for (int ks = 0; ks < 2; ++ks)                                                         \
        _Pragma("unroll")                                                                  \
        for (int n = 0; n < 4; ++n)                                                        \
            FB[ks][n] = *(const bf16x8*)((bb) + bRow[n] + aCh[ks]);                        \
} while (0)

#define MM(FA, FB) do {                                                                    \
    __builtin_amdgcn_s_setprio(1);                                                         \
    _Pragma("unroll")                                                                      \
    for (int ks = 0; ks < 2; ++ks)                                                         \
        _Pragma("unroll")                                                                  \
        for (int m = 0; m < 4; ++m)                                                        \
            _Pragma("unroll")                                                              \
            for (int n = 0; n < 4; ++n)                                                    \
                acc[m][n] = __builtin_amdgcn_mfma_f32_16x16x32_bf16(FA[ks][m], FB[ks][n],  \
                                                                    acc[m][n], 0, 0, 0);   \
    __builtin_amdgcn_s_setprio(0);                                                         \
} while (0)

#define BOUNDARY(T) do {                                                                   \
    if ((T) + 1 < NT) {                                                                    \
        if ((T) + 3 < NT)                                                                  \
            asm volatile("s_waitcnt lgkmcnt(0)\n\ts_waitcnt vmcnt(8)\n\ts_barrier" ::: "memory"); \
        else                                                                               \
            asm volatile("s_waitcnt lgkmcnt(0)\n\ts_waitcnt vmcnt(0)\n\ts_barrier" ::: "memory"); \
        __builtin_amdgcn_sched_barrier(0);                                                 \
    }                                                                                      \
} while (0)

#define BODY(T, FAc, FBc, FAn, FBn) do {                                                   \
    if ((T) + 3 < NT) STAGE(b0, (long)((T) + 3) << 6);                                     \
    if ((T) + 1 < NT) READF(FAn, FBn, b1);                                                 \
    MM(FAc, FBc);                                                                          \
    BOUNDARY(T);                                                                           \
    char* tmpp = b0; b0 = b1; b1 = b2; b2 = tmpp;                                          \
} while (0)

    bf16x8 FA0[2][4], FB0[2][4], FA1[2][4], FB1[2][4];

    // ---- prologue: stage tiles 0,1,2; drain 0,1 (leave 2 in flight); read frags0
    STAGE(b0, 0);
    STAGE(b1, 64);
    STAGE(b2, 128);
    asm volatile("s_waitcnt vmcnt(8)\n\ts_barrier" ::: "memory");
    __builtin_amdgcn_sched_barrier(0);
    READF(FA0, FB0, b0);
    asm volatile("s_waitcnt lgkmcnt(0)\n\ts_barrier" ::: "memory");
    __builtin_amdgcn_sched_barrier(0);

    for (int T = 0; T < NT; T += 2) {
        BODY(T,     FA0, FB0, FA1, FB1);
        BODY(T + 1, FA1, FB1, FA0, FB0);
    }

#undef STAGE
#undef READF
#undef MM
#undef BOUNDARY
#undef BODY

    // ---- epilogue: C/D layout col=lane&15, row=(lane>>4)*4+j
    const long crow = brow + wr * 64;
    const long ccol = bcol + wc * 64;
    const long cz = sCz * blockIdx.z;
#pragma unroll
    for (int m = 0; m < 4; ++m) {
#pragma unroll
        for (int n = 0; n < 4; ++n) {
#pragma unroll
            for (int j = 0; j < 4; ++j) {
                long r = crow + m * 16 + kq * 4 + j;
                long c = ccol + n * 16 + fr;
                float vv = acc[m][n][j];
                if (MODE == 0)      { vv += bias[c]; ((u16*)Cout)[cz + r * ldc + c] = f2bf(vv); }
                else if (MODE == 1) { vv += bias[r]; ((u16*)Cout)[cz + r * ldc + c] = f2bf(vv); }
                else if (MODE == 2) { ((_Float16*)Cout)[cz + r * ldc + c] = (_Float16)(vv * scale); }
                else                { ((float*)Cout)[cz + r * ldc + c] = vv; }
            }
        }
    }
}

// ---------------- row softmax: fp16 in -> bf16 out, in place, L=4096 ----------------
__global__ __launch_bounds__(256) void softmax_row(u16* __restrict__ S, int L) {
    const long row = blockIdx.x;
    u16* rp = S + row * L;
    const int t = threadIdx.x;
    const int lane = t & 63, wid = t >> 6;

    f16x8 h0 = *(const f16x8*)(rp + t * 16);
    f16x8 h1 = *(const f16x8*)(rp + t * 16 + 8);
    float x[16];
#pragma unroll
    for (int j = 0; j < 8; ++j) { x[j] = (float)h0[j]; x[8 + j] = (float)h1[j]; }

    float m = -1e30f;
#pragma unroll
    for (int j = 0; j < 16; ++j) m = fmaxf(m, x[j]);
#pragma unroll
    for (int o = 32; o; o >>= 1) m = fmaxf(m, __shfl_xor(m, o));

    __shared__ float redmax[4], redsum[4];
    if (lane == 0) redmax[wid] = m;
    __syncthreads();
    m = fmaxf(fmaxf(redmax[0], redmax[1]), fmaxf(redmax[2], redmax[3]));

    float e[16], s = 0.f;
#pragma unroll
    for (int j = 0; j < 16; ++j) { e[j] = __expf(x[j] - m); s += e[j]; }
#pragma unroll
    for (int o = 32; o; o >>= 1) s += __shfl_xor(s, o);
    if (lane == 0) redsum[wid] = s;
    __syncthreads();
    s = redsum[0] + redsum[1] + redsum[2] + redsum[3];
    float inv = 1.f / s;

    us8 o0, o1;
#pragma unroll
    for (int j = 0; j < 8; ++j) { o0[j] = f2bf(e[j] * inv); o1[j] = f2bf(e[8 + j] * inv); }
    *(us8*)(rp + t * 16) = o0;
    *(us8*)(rp + t * 16 + 8) = o1;
}

extern "C" void kernel_launch(void* const* d_in, const int* in_sizes, int n_in,
                              void* d_out, int out_size, void* d_ws, size_t ws_size,
                              hipStream_t stream) {
    (void)in_sizes; (void)n_in; (void)out_size; (void)ws_size;
    const float* q  = (const float*)d_in[0];
    const float* k  = (const float*)d_in[1];
    const float* v  = (const float*)d_in[2];
    const float* Wq = (const float*)d_in[3];
    const float* bq = (const float*)d_in[4];
    const float* Wk = (const float*)d_in[5];
    const float* bk = (const float*)d_in[6];
    const float* Wv = (const float*)d_in[7];
    const float* bv = (const float*)d_in[8];
    float* out = (float*)d_out;

    constexpr long MB = 1l << 20;
    char* ws = (char*)d_ws;
    u16* pq  = (u16*)(ws + 0 * MB);     // 32 MB  [16384,1024] bf16
    u16* pk  = (u16*)(ws + 32 * MB);    // 32 MB
    u16* pvT = (u16*)(ws + 64 * MB);    // 32 MB  [1024,16384] bf16 (pv transposed)
    u16* Wqb = (u16*)(ws + 96 * MB);    // 2 MB
    u16* Wkb = (u16*)(ws + 98 * MB);    // 2 MB
    u16* Wvb = (u16*)(ws + 100 * MB);   // 2 MB
    u16* qb  = (u16*)(ws + 104 * MB);   // 32 MB (dead after pq GEMM)
    u16* kb  = (u16*)(ws + 136 * MB);   // 32 MB (dead after pk GEMM)
    u16* vb  = (u16*)(ws + 168 * MB);   // 32 MB -> ws end = 200 MB
    u16* S2  = (u16*)(ws + 104 * MB);   // 64 MB (2 batches), aliases qb+kb (dead)

    const int L = 4096, E = 1024, NB = 4;
    const int n8_x = (NB * L * E) / 8;
    const int n8_w = (E * E) / 8;

    cvt_f32_bf16<<<2048, 256, 0, stream>>>(q, qb, n8_x);
    cvt_f32_bf16<<<2048, 256, 0, stream>>>(k, kb, n8_x);
    cvt_f32_bf16<<<2048, 256, 0, stream>>>(v, vb, n8_x);
    cvt_f32_bf16<<<512, 256, 0, stream>>>(Wq, Wqb, n8_w);
    cvt_f32_bf16<<<512, 256, 0, stream>>>(Wk, Wkb, n8_w);
    cvt_f32_bf16<<<512, 256, 0, stream>>>(Wv, Wvb, n8_w);

    // projections: pq = q@Wq^T + bq   (M=16384 -> gy=128, N=1024 -> gx=8)
    dim3 gproj(8, 128, 1);
    gemm128p<0><<<gproj, 256, 0, stream>>>(qb, Wqb, pq, bq, 1.f, E, E, E, E, 0, 0, 0);
    gemm128p<0><<<gproj, 256, 0, stream>>>(kb, Wkb, pk, bk, 1.f, E, E, E, E, 0, 0, 0);
    // pvT = Wv @ v^T + bv[row]   (M=1024 -> gy=8, N=16384 -> gx=128)
    dim3 gpv(128, 8, 1);
    gemm128p<1><<<gpv, 256, 0, stream>>>(Wvb, vb, pvT, bv, 1.f, E, E, E, NB * L, 0, 0, 0);

    const float scale = 0.03125f;  // 1/sqrt(1024)
    for (int p = 0; p < 2; ++p) {
        const long zb = p * 2;
        // S = pq @ pk^T * scale -> fp16   (M=N=4096 -> gy=32, gx=32; z=2 batches)
        dim3 gs(32, 32, 2);
        gemm128p<2><<<gs, 256, 0, stream>>>(pq + zb * L * E, pk + zb * L * E, (void*)S2,
                                            nullptr, scale, E, E, E, L,
                                            (long)L * E, (long)L * E, (long)L * L);
        // softmax over 2*L rows, in place fp16 -> bf16
        softmax_row<<<2 * L, 256, 0, stream>>>(S2, L);
        // out = attn @ pvT^T   (M=4096 -> gy=32, N=1024 -> gx=8; z=2)
        dim3 gp(8, 32, 2);
        gemm128p<3><<<gp, 256, 0, stream>>>(S2, pvT + zb * L, out + zb * L * E,
                                            nullptr, 1.f, L, L, NB * L, E,
                                            (long)L * L, (long)L, (long)L * E);
    }
}

// Round 7
// 475.587 us; speedup vs baseline: 1.5106x; 1.5106x over previous
//
#include <hip/hip_runtime.h>

typedef unsigned short u16;
typedef __bf16  bf16x8 __attribute__((ext_vector_type(8)));
typedef float   f32x4  __attribute__((ext_vector_type(4)));
typedef unsigned short us8 __attribute__((ext_vector_type(8)));
typedef _Float16 f16x8 __attribute__((ext_vector_type(8)));
typedef float   fl4   __attribute__((ext_vector_type(4)));

#define AS1 __attribute__((address_space(1)))
#define AS3 __attribute__((address_space(3)))

__device__ __forceinline__ u16 f2bf(float f) {
    union { float f; unsigned u; } x; x.f = f;
    unsigned r = x.u + 0x7fffu + ((x.u >> 16) & 1u);
    return (u16)(r >> 16);
}

// ---------------- fp32 -> bf16 cast, vectorized ----------------
__global__ __launch_bounds__(256) void cvt_f32_bf16(const float* __restrict__ in,
                                                    u16* __restrict__ out, int n8) {
    int i = blockIdx.x * blockDim.x + threadIdx.x;
    int stride = gridDim.x * blockDim.x;
    for (; i < n8; i += stride) {
        const fl4* p = (const fl4*)(in + (long)i * 8);
        fl4 a = p[0], b = p[1];
        us8 o;
#pragma unroll
        for (int j = 0; j < 4; ++j) { o[j] = f2bf(a[j]); o[4 + j] = f2bf(b[j]); }
        *(us8*)(out + (long)i * 8) = o;
    }
}

// ---------------- 256x256 tile bf16 GEMM, C = A * B^T ----------------
// R5's provably race-free drain-all schedule, scaled to the m201 geometry:
// 8 waves (2M x 4N), per-wave output 128x64 -> 24 ds_read_b128 per 64 MFMA
// (0.375 reads/MFMA vs 0.5 at 128^2) so the LDS pipe no longer dominates.
// K-tile body split in two m-halves to bound frag VGPRs (~192 live + acc).
// 2 waves/SIMD (512 thr, 1 block/CU) preserve cross-wave ds/MFMA overlap.
// MODE 0: bf16 out + bias[col]; MODE 1: bf16 out + bias[row];
// MODE 2: fp16 out * scale;     MODE 3: fp32 out.
template <int MODE>
__global__ __launch_bounds__(512, 2) void gemm256d(const u16* __restrict__ A,
                                                   const u16* __restrict__ B,
                                                   void* __restrict__ Cout,
                                                   const float* __restrict__ bias,
                                                   float scale, int K,
                                                   int lda, int ldb, int ldc,
                                                   long sAz, long sBz, long sCz) {
    // per buffer: A 256x64 bf16 = 32 KB, B 256x64 bf16 = 32 KB -> 64 KB; x2 = 128 KiB
    __shared__ alignas(16) char lds8[2 * 65536];

    const int t    = threadIdx.x;
    const int lane = t & 63;
    const int wid  = t >> 6;      // 0..7
    const int wr   = wid >> 2;    // 0..1  (128-row slice of 256)
    const int wc   = wid & 3;     // 0..3  (64-col slice of 256)
    const int fr   = lane & 15;
    const int kq   = lane >> 4;

    // XCD-bijective block swizzle (nwg % 8 == 0 for all our launches)
    const int gx  = gridDim.x;
    const int nwg = gx * gridDim.y;
    const int wg  = blockIdx.y * gx + blockIdx.x;
    const int swz = (wg & 7) * (nwg >> 3) + (wg >> 3);
    const long brow = (long)(swz / gx) * 256;
    const long bcol = (long)(swz % gx) * 256;

    const u16* Az = A + sAz * blockIdx.z;
    const u16* Bz = B + sBz * blockIdx.z;

    // staging: dest = r*8192 + t*16 linear (4 rounds x 8 KB per matrix);
    // source chunk pre-swizzled (t&7)^(trow&7) so physical chunk p holds
    // logical chunk p^(row&7).
    const int trow = t >> 3;                  // 0..63
    const int tc8  = ((t & 7) ^ (trow & 7)) * 8;
    long offA[4], offB[4];
#pragma unroll
    for (int r = 0; r < 4; ++r) offA[r] = (brow + r * 64 + trow) * (long)lda + tc8;
#pragma unroll
    for (int r = 0; r < 4; ++r) offB[r] = (bcol + r * 64 + trow) * (long)ldb + tc8;

    // lane read offsets (swizzled): byte = row*128 + ((ksub*4+kq)^(row&7))*16
    int aRow[8], bRow[4], aCh[2];
#pragma unroll
    for (int m = 0; m < 8; ++m) aRow[m] = (wr * 128 + m * 16 + fr) * 128;
#pragma unroll
    for (int n = 0; n < 4; ++n) bRow[n] = 65536 / 2 + (wc * 64 + n * 16 + fr) * 128;
#pragma unroll
    for (int ks = 0; ks < 2; ++ks) aCh[ks] = (((ks << 2) | kq) ^ (fr & 7)) * 16;

    const int NT = K >> 6;
    f32x4 acc[8][4] = {};

    // ---- prologue: stage tile 0 into buffer 0, full drain
    {
        char* bb0 = lds8;
#pragma unroll
        for (int r = 0; r < 4; ++r)
            __builtin_amdgcn_global_load_lds((const AS1 unsigned*)(Az + offA[r]),
                                             (AS3 unsigned*)(bb0 + r * 8192 + t * 16), 16, 0, 0);
#pragma unroll
        for (int r = 0; r < 4; ++r)
            __builtin_amdgcn_global_load_lds((const AS1 unsigned*)(Bz + offB[r]),
                                             (AS3 unsigned*)(bb0 + 32768 + r * 8192 + t * 16), 16, 0, 0);
    }
    __syncthreads();

    int cur = 0;
    for (int T = 0; T < NT; ++T) {
        char* bb  = lds8 + cur * 65536;
        char* bbn = lds8 + (cur ^ 1) * 65536;

        // ---- issue next-tile stage FIRST: latency covered by this tile's work.
        if (T + 1 < NT) {
            const long kcol = (long)(T + 1) << 6;
#pragma unroll
            for (int r = 0; r < 4; ++r)
                __builtin_amdgcn_global_load_lds((const AS1 unsigned*)(Az + offA[r] + kcol),
                                                 (AS3 unsigned*)(bbn + r * 8192 + t * 16), 16, 0, 0);
#pragma unroll
            for (int r = 0; r < 4; ++r)
                __builtin_amdgcn_global_load_lds((const AS1 unsigned*)(Bz + offB[r] + kcol),
                                                 (AS3 unsigned*)(bbn + 32768 + r * 8192 + t * 16), 16, 0, 0);
        }

        // ---- m-half 0: read B(all) + A(m0..3), 16 x ds_read_b128, 32 MFMA
        bf16x8 bfv[2][4], afl[2][4], afh[2][4];
#pragma unroll
        for (int ks = 0; ks < 2; ++ks)
#pragma unroll
            for (int n = 0; n < 4; ++n)
                bfv[ks][n] = *(const bf16x8*)(bb + bRow[n] + aCh[ks]);
#pragma unroll
        for (int ks = 0; ks < 2; ++ks)
#pragma unroll
            for (int m = 0; m < 4; ++m)
                afl[ks][m] = *(const bf16x8*)(bb + aRow[m] + aCh[ks]);

        asm volatile("s_waitcnt lgkmcnt(0)" ::: "memory");
        __builtin_amdgcn_sched_barrier(0);
        __builtin_amdgcn_s_setprio(1);
#pragma unroll
        for (int ks = 0; ks < 2; ++ks)
#pragma unroll
            for (int m = 0; m < 4; ++m)
#pragma unroll
                for (int n = 0; n < 4; ++n)
                    acc[m][n] = __builtin_amdgcn_mfma_f32_16x16x32_bf16(afl[ks][m], bfv[ks][n], acc[m][n], 0, 0, 0);
        __builtin_amdgcn_s_setprio(0);

        // ---- m-half 1: read A(m4..7), 8 x ds_read_b128, 32 MFMA (B reused)
#pragma unroll
        for (int ks = 0; ks < 2; ++ks)
#pragma unroll
            for (int m = 0; m < 4; ++m)
                afh[ks][m] = *(const bf16x8*)(bb + aRow[4 + m] + aCh[ks]);

        asm volatile("s_waitcnt lgkmcnt(0)" ::: "memory");
        __builtin_amdgcn_sched_barrier(0);
        __builtin_amdgcn_s_setprio(1);
#pragma unroll
        for (int ks = 0; ks < 2; ++ks)
#pragma unroll
            for (int m = 0; m < 4; ++m)
#pragma unroll
                for (int n = 0; n < 4; ++n)
                    acc[4 + m][n] = __builtin_amdgcn_mfma_f32_16x16x32_bf16(afh[ks][m], bfv[ks][n], acc[4 + m][n], 0, 0, 0);
        __builtin_amdgcn_s_setprio(0);
        __builtin_amdgcn_sched_barrier(0);

        // full drain: stage loads landed, all LDS reads done -> next tile safe
        __syncthreads();
        cur ^= 1;
    }

    // ---- epilogue: C/D layout col=lane&15, row=(lane>>4)*4+j
    const long crow = brow + wr * 128;
    const long ccol = bcol + wc * 64;
    const long cz = sCz * blockIdx.z;
#pragma unroll
    for (int m = 0; m < 8; ++m) {
#pragma unroll
        for (int n = 0; n < 4; ++n) {
#pragma unroll
            for (int j = 0; j < 4; ++j) {
                long r = crow + m * 16 + kq * 4 + j;
                long c = ccol + n * 16 + fr;
                float vv = acc[m][n][j];
                if (MODE == 0)      { vv += bias[c]; ((u16*)Cout)[cz + r * ldc + c] = f2bf(vv); }
                else if (MODE == 1) { vv += bias[r]; ((u16*)Cout)[cz + r * ldc + c] = f2bf(vv); }
                else if (MODE == 2) { ((_Float16*)Cout)[cz + r * ldc + c] = (_Float16)(vv * scale); }
                else                { ((float*)Cout)[cz + r * ldc + c] = vv; }
            }
        }
    }
}

// ---------------- 128x128 tile bf16 GEMM (R5, proven) ----------------
template <int MODE>
__global__ __launch_bounds__(256, 2) void gemm128(const u16* __restrict__ A,
                                                  const u16* __restrict__ B,
                                                  void* __restrict__ Cout,
                                                  const float* __restrict__ bias,
                                                  float scale, int K,
                                                  int lda, int ldb, int ldc,
                                                  long sAz, long sBz, long sCz) {
    __shared__ alignas(16) char lds8[2 * 32768];

    const int t    = threadIdx.x;
    const int lane = t & 63;
    const int wid  = t >> 6;
    const int wr   = wid >> 1;
    const int wc   = wid & 1;
    const int fr   = lane & 15;
    const int kq   = lane >> 4;

    const int gx  = gridDim.x;
    const int nwg = gx * gridDim.y;
    const int wg  = blockIdx.y * gx + blockIdx.x;
    const int swz = (wg & 7) * (nwg >> 3) + (wg >> 3);
    const long brow = (long)(swz / gx) * 128;
    const long bcol = (long)(swz % gx) * 128;

    const u16* Az = A + sAz * blockIdx.z;
    const u16* Bz = B + sBz * blockIdx.z;

    const int trow = t >> 3;
    const int tc8  = ((t & 7) ^ (trow & 7)) * 8;
    long offA[4], offB[4];
#pragma unroll
    for (int r = 0; r < 4; ++r) offA[r] = (brow + r * 32 + trow) * (long)lda + tc8;
#pragma unroll
    for (int r = 0; r < 4; ++r) offB[r] = (bcol + r * 32 + trow) * (long)ldb + tc8;

    int aRow[4], bRow[4], aCh[2];
#pragma unroll
    for (int m = 0; m < 4; ++m) aRow[m] = (wr * 64 + m * 16 + fr) * 128;
#pragma unroll
    for (int n = 0; n < 4; ++n) bRow[n] = 16384 + (wc * 64 + n * 16 + fr) * 128;
#pragma unroll
    for (int ks = 0; ks < 2; ++ks) aCh[ks] = (((ks << 2) | kq) ^ (fr & 7)) * 16;

    const int NT = K >> 6;
    f32x4 acc[4][4] = {};

    {
        char* bb0 = lds8;
#pragma unroll
        for (int r = 0; r < 4; ++r)
            __builtin_amdgcn_global_load_lds((const AS1 unsigned*)(Az + offA[r]),
                                             (AS3 unsigned*)(bb0 + r * 4096 + t * 16), 16, 0, 0);
#pragma unroll
        for (int r = 0; r < 4; ++r)
            __builtin_amdgcn_global_load_lds((const AS1 unsigned*)(Bz + offB[r]),
                                             (AS3 unsigned*)(bb0 + 16384 + r * 4096 + t * 16), 16, 0, 0);
    }
    __syncthreads();

    int cur = 0;
    for (int T = 0; T < NT; ++T) {
        char* bb  = lds8 + cur * 32768;
        char* bbn = lds8 + (cur ^ 1) * 32768;

        if (T + 1 < NT) {
            const long kcol = (long)(T + 1) << 6;
#pragma unroll
            for (int r = 0; r < 4; ++r)
                __builtin_amdgcn_global_load_lds((const AS1 unsigned*)(Az + offA[r] + kcol),
                                                 (AS3 unsigned*)(bbn + r * 4096 + t * 16), 16, 0, 0);
#pragma unroll
            for (int r = 0; r < 4; ++r)
                __builtin_amdgcn_global_load_lds((const AS1 unsigned*)(Bz + offB[r] + kcol),
                                                 (AS3 unsigned*)(bbn + 16384 + r * 4096 + t * 16), 16, 0, 0);
        }

        bf16x8 af[2][4], bfv[2][4];
#pragma unroll
        for (int ks = 0; ks < 2; ++ks)
#pragma unroll
            for (int m = 0; m < 4; ++m)
                af[ks][m] = *(const bf16x8*)(bb + aRow[m] + aCh[ks]);
#pragma unroll
        for (int ks = 0; ks < 2; ++ks)
#pragma unroll
            for (int n = 0; n < 4; ++n)
                bfv[ks][n] = *(const bf16x8*)(bb + bRow[n] + aCh[ks]);

        asm volatile("s_waitcnt lgkmcnt(0)" ::: "memory");
        __builtin_amdgcn_sched_barrier(0);
        __builtin_amdgcn_s_setprio(1);
#pragma unroll
        for (int ks = 0; ks < 2; ++ks)
#pragma unroll
            for (int m = 0; m < 4; ++m)
#pragma unroll
                for (int n = 0; n < 4; ++n)
                    acc[m][n] = __builtin_amdgcn_mfma_f32_16x16x32_bf16(af[ks][m], bfv[ks][n], acc[m][n], 0, 0, 0);
        __builtin_amdgcn_s_setprio(0);
        __builtin_amdgcn_sched_barrier(0);

        __syncthreads();
        cur ^= 1;
    }

    const long crow = brow + wr * 64;
    const long ccol = bcol + wc * 64;
    const long cz = sCz * blockIdx.z;
#pragma unroll
    for (int m = 0; m < 4; ++m) {
#pragma unroll
        for (int n = 0; n < 4; ++n) {
#pragma unroll
            for (int j = 0; j < 4; ++j) {
                long r = crow + m * 16 + kq * 4 + j;
                long c = ccol + n * 16 + fr;
                float vv = acc[m][n][j];
                if (MODE == 0)      { vv += bias[c]; ((u16*)Cout)[cz + r * ldc + c] = f2bf(vv); }
                else if (MODE == 1) { vv += bias[r]; ((u16*)Cout)[cz + r * ldc + c] = f2bf(vv); }
                else if (MODE == 2) { ((_Float16*)Cout)[cz + r * ldc + c] = (_Float16)(vv * scale); }
                else                { ((float*)Cout)[cz + r * ldc + c] = vv; }
            }
        }
    }
}

// ---------------- row softmax: fp16 in -> bf16 out, in place, L=4096 ----------------
__global__ __launch_bounds__(256) void softmax_row(u16* __restrict__ S, int L) {
    const long row = blockIdx.x;
    u16* rp = S + row * L;
    const int t = threadIdx.x;
    const int lane = t & 63, wid = t >> 6;

    f16x8 h0 = *(const f16x8*)(rp + t * 16);
    f16x8 h1 = *(const f16x8*)(rp + t * 16 + 8);
    float x[16];
#pragma unroll
    for (int j = 0; j < 8; ++j) { x[j] = (float)h0[j]; x[8 + j] = (float)h1[j]; }

    float m = -1e30f;
#pragma unroll
    for (int j = 0; j < 16; ++j) m = fmaxf(m, x[j]);
#pragma unroll
    for (int o = 32; o; o >>= 1) m = fmaxf(m, __shfl_xor(m, o));

    __shared__ float redmax[4], redsum[4];
    if (lane == 0) redmax[wid] = m;
    __syncthreads();
    m = fmaxf(fmaxf(redmax[0], redmax[1]), fmaxf(redmax[2], redmax[3]));

    float e[16], s = 0.f;
#pragma unroll
    for (int j = 0; j < 16; ++j) { e[j] = __expf(x[j] - m); s += e[j]; }
#pragma unroll
    for (int o = 32; o; o >>= 1) s += __shfl_xor(s, o);
    if (lane == 0) redsum[wid] = s;
    __syncthreads();
    s = redsum[0] + redsum[1] + redsum[2] + redsum[3];
    float inv = 1.f / s;

    us8 o0, o1;
#pragma unroll
    for (int j = 0; j < 8; ++j) { o0[j] = f2bf(e[j] * inv); o1[j] = f2bf(e[8 + j] * inv); }
    *(us8*)(rp + t * 16) = o0;
    *(us8*)(rp + t * 16 + 8) = o1;
}

extern "C" void kernel_launch(void* const* d_in, const int* in_sizes, int n_in,
                              void* d_out, int out_size, void* d_ws, size_t ws_size,
                              hipStream_t stream) {
    (void)in_sizes; (void)n_in; (void)out_size; (void)ws_size;
    const float* q  = (const float*)d_in[0];
    const float* k  = (const float*)d_in[1];
    const float* v  = (const float*)d_in[2];
    const float* Wq = (const float*)d_in[3];
    const float* bq = (const float*)d_in[4];
    const float* Wk = (const float*)d_in[5];
    const float* bk = (const float*)d_in[6];
    const float* Wv = (const float*)d_in[7];
    const float* bv = (const float*)d_in[8];
    float* out = (float*)d_out;

    constexpr long MB = 1l << 20;
    char* ws = (char*)d_ws;
    u16* pq  = (u16*)(ws + 0 * MB);     // 32 MB  [16384,1024] bf16
    u16* pk  = (u16*)(ws + 32 * MB);    // 32 MB
    u16* pvT = (u16*)(ws + 64 * MB);    // 32 MB  [1024,16384] bf16 (pv transposed)
    u16* Wqb = (u16*)(ws + 96 * MB);    // 2 MB
    u16* Wkb = (u16*)(ws + 98 * MB);    // 2 MB
    u16* Wvb = (u16*)(ws + 100 * MB);   // 2 MB
    u16* qb  = (u16*)(ws + 104 * MB);   // 32 MB (dead after pq GEMM)
    u16* kb  = (u16*)(ws + 136 * MB);   // 32 MB (dead after pk GEMM)
    u16* vb  = (u16*)(ws + 168 * MB);   // 32 MB -> ws end = 200 MB
    u16* S2  = (u16*)(ws + 104 * MB);   // 64 MB (2 batches), aliases qb+kb (dead)

    const int L = 4096, E = 1024, NB = 4;
    const int n8_x = (NB * L * E) / 8;
    const int n8_w = (E * E) / 8;

    cvt_f32_bf16<<<2048, 256, 0, stream>>>(q, qb, n8_x);
    cvt_f32_bf16<<<2048, 256, 0, stream>>>(k, kb, n8_x);
    cvt_f32_bf16<<<2048, 256, 0, stream>>>(v, vb, n8_x);
    cvt_f32_bf16<<<512, 256, 0, stream>>>(Wq, Wqb, n8_w);
    cvt_f32_bf16<<<512, 256, 0, stream>>>(Wk, Wkb, n8_w);
    cvt_f32_bf16<<<512, 256, 0, stream>>>(Wv, Wvb, n8_w);

    // projections: pq = q@Wq^T + bq   (M=16384 -> gy=64, N=1024 -> gx=4) 256 blocks
    dim3 gproj(4, 64, 1);
    gemm256d<0><<<gproj, 512, 0, stream>>>(qb, Wqb, pq, bq, 1.f, E, E, E, E, 0, 0, 0);
    gemm256d<0><<<gproj, 512, 0, stream>>>(kb, Wkb, pk, bk, 1.f, E, E, E, E, 0, 0, 0);
    // pvT = Wv @ v^T + bv[row]   (M=1024 -> gy=4, N=16384 -> gx=64) 256 blocks
    dim3 gpv(64, 4, 1);
    gemm256d<1><<<gpv, 512, 0, stream>>>(Wvb, vb, pvT, bv, 1.f, E, E, E, NB * L, 0, 0, 0);

    const float scale = 0.03125f;  // 1/sqrt(1024)
    for (int p = 0; p < 2; ++p) {
        const long zb = p * 2;
        // S = pq @ pk^T * scale -> fp16   (M=N=4096 -> 16x16; z=2) 512 blocks
        dim3 gs(16, 16, 2);
        gemm256d<2><<<gs, 512, 0, stream>>>(pq + zb * L * E, pk + zb * L * E, (void*)S2,
                                            nullptr, scale, E, E, E, L,
                                            (long)L * E, (long)L * E, (long)L * L);
        // softmax over 2*L rows, in place fp16 -> bf16
        softmax_row<<<2 * L, 256, 0, stream>>>(S2, L);
        // out = attn @ pvT^T   (M=4096 -> gy=32, N=1024 -> gx=8; z=2) on gemm128
        dim3 gp(8, 32, 2);
        gemm128<3><<<gp, 256, 0, stream>>>(S2, pvT + zb * L, out + zb * L * E,
                                           nullptr, 1.f, L, L, NB * L, E,
                                           (long)L * L, (long)L, (long)L * E);
    }
}

// Round 8
// 451.037 us; speedup vs baseline: 1.5928x; 1.0544x over previous
//
#include <hip/hip_runtime.h>

typedef unsigned short u16;
typedef __bf16  bf16x8 __attribute__((ext_vector_type(8)));
typedef float   f32x4  __attribute__((ext_vector_type(4)));
typedef unsigned short us8 __attribute__((ext_vector_type(8)));
typedef _Float16 f16x8 __attribute__((ext_vector_type(8)));
typedef float   fl4   __attribute__((ext_vector_type(4)));

#define AS1 __attribute__((address_space(1)))
#define AS3 __attribute__((address_space(3)))

__device__ __forceinline__ u16 f2bf(float f) {
    union { float f; unsigned u; } x; x.f = f;
    unsigned r = x.u + 0x7fffu + ((x.u >> 16) & 1u);
    return (u16)(r >> 16);
}

// ---------------- fp32 -> bf16 cast, 3 tensors per launch (blockIdx.y) ----------------
__global__ __launch_bounds__(256) void cvt3_f32_bf16(const float* __restrict__ in0,
                                                     const float* __restrict__ in1,
                                                     const float* __restrict__ in2,
                                                     u16* __restrict__ out0,
                                                     u16* __restrict__ out1,
                                                     u16* __restrict__ out2, int n8) {
    const float* in = blockIdx.y == 0 ? in0 : (blockIdx.y == 1 ? in1 : in2);
    u16* out        = blockIdx.y == 0 ? out0 : (blockIdx.y == 1 ? out1 : out2);
    int i = blockIdx.x * blockDim.x + threadIdx.x;
    int stride = gridDim.x * blockDim.x;
    for (; i < n8; i += stride) {
        const fl4* p = (const fl4*)(in + (long)i * 8);
        fl4 a = p[0], b = p[1];
        us8 o;
#pragma unroll
        for (int j = 0; j < 4; ++j) { o[j] = f2bf(a[j]); o[4 + j] = f2bf(b[j]); }
        *(us8*)(out + (long)i * 8) = o;
    }
}

// ---------------- 256x256 tile bf16 GEMM, C = A * B^T ----------------
// Drain-all schedule (provably race-free): stage T+1 first, plain-C++ ds_reads,
// MFMA, one __syncthreads per K-tile. NO explicit lgkmcnt/sched_barrier pins —
// the compiler's scoreboard emits precise lgkmcnt(N) and interleaves ds_reads
// with MFMAs (m97/m141 lessons). 8 waves (2M x 4N), per-wave 128x64.
// MODE 0: bf16 out + bias[col]; MODE 1: bf16 out + bias[row];
// MODE 2: fp16 out * scale;     MODE 3: fp32 out.
template <int MODE>
__global__ __launch_bounds__(512, 2) void gemm256d(const u16* __restrict__ A,
                                                   const u16* __restrict__ B,
                                                   void* __restrict__ Cout,
                                                   const float* __restrict__ bias,
                                                   float scale, int K,
                                                   int lda, int ldb, int ldc,
                                                   long sAz, long sBz, long sCz) {
    __shared__ alignas(16) char lds8[2 * 65536];

    const int t    = threadIdx.x;
    const int lane = t & 63;
    const int wid  = t >> 6;
    const int wr   = wid >> 2;    // 0..1
    const int wc   = wid & 3;     // 0..3
    const int fr   = lane & 15;
    const int kq   = lane >> 4;

    const int gx  = gridDim.x;
    const int nwg = gx * gridDim.y;
    const int wg  = blockIdx.y * gx + blockIdx.x;
    const int swz = (wg & 7) * (nwg >> 3) + (wg >> 3);
    const long brow = (long)(swz / gx) * 256;
    const long bcol = (long)(swz % gx) * 256;

    const u16* Az = A + sAz * blockIdx.z;
    const u16* Bz = B + sBz * blockIdx.z;

    const int trow = t >> 3;
    const int tc8  = ((t & 7) ^ (trow & 7)) * 8;
    long offA[4], offB[4];
#pragma unroll
    for (int r = 0; r < 4; ++r) offA[r] = (brow + r * 64 + trow) * (long)lda + tc8;
#pragma unroll
    for (int r = 0; r < 4; ++r) offB[r] = (bcol + r * 64 + trow) * (long)ldb + tc8;

    int aRow[8], bRow[4], aCh[2];
#pragma unroll
    for (int m = 0; m < 8; ++m) aRow[m] = (wr * 128 + m * 16 + fr) * 128;
#pragma unroll
    for (int n = 0; n < 4; ++n) bRow[n] = 32768 + (wc * 64 + n * 16 + fr) * 128;
#pragma unroll
    for (int ks = 0; ks < 2; ++ks) aCh[ks] = (((ks << 2) | kq) ^ (fr & 7)) * 16;

    const int NT = K >> 6;
    f32x4 acc[8][4] = {};

    {
        char* bb0 = lds8;
#pragma unroll
        for (int r = 0; r < 4; ++r)
            __builtin_amdgcn_global_load_lds((const AS1 unsigned*)(Az + offA[r]),
                                             (AS3 unsigned*)(bb0 + r * 8192 + t * 16), 16, 0, 0);
#pragma unroll
        for (int r = 0; r < 4; ++r)
            __builtin_amdgcn_global_load_lds((const AS1 unsigned*)(Bz + offB[r]),
                                             (AS3 unsigned*)(bb0 + 32768 + r * 8192 + t * 16), 16, 0, 0);
    }
    __syncthreads();

    int cur = 0;
    for (int T = 0; T < NT; ++T) {
        char* bb  = lds8 + cur * 65536;
        char* bbn = lds8 + (cur ^ 1) * 65536;

        if (T + 1 < NT) {
            const long kcol = (long)(T + 1) << 6;
#pragma unroll
            for (int r = 0; r < 4; ++r)
                __builtin_amdgcn_global_load_lds((const AS1 unsigned*)(Az + offA[r] + kcol),
                                                 (AS3 unsigned*)(bbn + r * 8192 + t * 16), 16, 0, 0);
#pragma unroll
            for (int r = 0; r < 4; ++r)
                __builtin_amdgcn_global_load_lds((const AS1 unsigned*)(Bz + offB[r] + kcol),
                                                 (AS3 unsigned*)(bbn + 32768 + r * 8192 + t * 16), 16, 0, 0);
        }

        // m-half 0: B(all) + A(m0..3); compiler schedules lgkmcnt precisely
        bf16x8 bfv[2][4], afl[2][4], afh[2][4];
#pragma unroll
        for (int ks = 0; ks < 2; ++ks)
#pragma unroll
            for (int n = 0; n < 4; ++n)
                bfv[ks][n] = *(const bf16x8*)(bb + bRow[n] + aCh[ks]);
#pragma unroll
        for (int ks = 0; ks < 2; ++ks)
#pragma unroll
            for (int m = 0; m < 4; ++m)
                afl[ks][m] = *(const bf16x8*)(bb + aRow[m] + aCh[ks]);

        __builtin_amdgcn_s_setprio(1);
#pragma unroll
        for (int ks = 0; ks < 2; ++ks)
#pragma unroll
            for (int m = 0; m < 4; ++m)
#pragma unroll
                for (int n = 0; n < 4; ++n)
                    acc[m][n] = __builtin_amdgcn_mfma_f32_16x16x32_bf16(afl[ks][m], bfv[ks][n], acc[m][n], 0, 0, 0);
        __builtin_amdgcn_s_setprio(0);

        // m-half 1: A(m4..7), B reused
#pragma unroll
        for (int ks = 0; ks < 2; ++ks)
#pragma unroll
            for (int m = 0; m < 4; ++m)
                afh[ks][m] = *(const bf16x8*)(bb + aRow[4 + m] + aCh[ks]);

        __builtin_amdgcn_s_setprio(1);
#pragma unroll
        for (int ks = 0; ks < 2; ++ks)
#pragma unroll
            for (int m = 0; m < 4; ++m)
#pragma unroll
                for (int n = 0; n < 4; ++n)
                    acc[4 + m][n] = __builtin_amdgcn_mfma_f32_16x16x32_bf16(afh[ks][m], bfv[ks][n], acc[4 + m][n], 0, 0, 0);
        __builtin_amdgcn_s_setprio(0);

        __syncthreads();
        cur ^= 1;
    }

    const long crow = brow + wr * 128;
    const long ccol = bcol + wc * 64;
    const long cz = sCz * blockIdx.z;
#pragma unroll
    for (int m = 0; m < 8; ++m) {
#pragma unroll
        for (int n = 0; n < 4; ++n) {
#pragma unroll
            for (int j = 0; j < 4; ++j) {
                long r = crow + m * 16 + kq * 4 + j;
                long c = ccol + n * 16 + fr;
                float vv = acc[m][n][j];
                if (MODE == 0)      { vv += bias[c]; ((u16*)Cout)[cz + r * ldc + c] = f2bf(vv); }
                else if (MODE == 1) { vv += bias[r]; ((u16*)Cout)[cz + r * ldc + c] = f2bf(vv); }
                else if (MODE == 2) { ((_Float16*)Cout)[cz + r * ldc + c] = (_Float16)(vv * scale); }
                else                { ((float*)Cout)[cz + r * ldc + c] = vv; }
            }
        }
    }
}

// ---------------- 128x128 tile bf16 GEMM (R5, proven — fallback path) ----------------
template <int MODE>
__global__ __launch_bounds__(256, 2) void gemm128(const u16* __restrict__ A,
                                                  const u16* __restrict__ B,
                                                  void* __restrict__ Cout,
                                                  const float* __restrict__ bias,
                                                  float scale, int K,
                                                  int lda, int ldb, int ldc,
                                                  long sAz, long sBz, long sCz) {
    __shared__ alignas(16) char lds8[2 * 32768];

    const int t    = threadIdx.x;
    const int lane = t & 63;
    const int wid  = t >> 6;
    const int wr   = wid >> 1;
    const int wc   = wid & 1;
    const int fr   = lane & 15;
    const int kq   = lane >> 4;

    const int gx  = gridDim.x;
    const int nwg = gx * gridDim.y;
    const int wg  = blockIdx.y * gx + blockIdx.x;
    const int swz = (wg & 7) * (nwg >> 3) + (wg >> 3);
    const long brow = (long)(swz / gx) * 128;
    const long bcol = (long)(swz % gx) * 128;

    const u16* Az = A + sAz * blockIdx.z;
    const u16* Bz = B + sBz * blockIdx.z;

    const int trow = t >> 3;
    const int tc8  = ((t & 7) ^ (trow & 7)) * 8;
    long offA[4], offB[4];
#pragma unroll
    for (int r = 0; r < 4; ++r) offA[r] = (brow + r * 32 + trow) * (long)lda + tc8;
#pragma unroll
    for (int r = 0; r < 4; ++r) offB[r] = (bcol + r * 32 + trow) * (long)ldb + tc8;

    int aRow[4], bRow[4], aCh[2];
#pragma unroll
    for (int m = 0; m < 4; ++m) aRow[m] = (wr * 64 + m * 16 + fr) * 128;
#pragma unroll
    for (int n = 0; n < 4; ++n) bRow[n] = 16384 + (wc * 64 + n * 16 + fr) * 128;
#pragma unroll
    for (int ks = 0; ks < 2; ++ks) aCh[ks] = (((ks << 2) | kq) ^ (fr & 7)) * 16;

    const int NT = K >> 6;
    f32x4 acc[4][4] = {};

    {
        char* bb0 = lds8;
#pragma unroll
        for (int r = 0; r < 4; ++r)
            __builtin_amdgcn_global_load_lds((const AS1 unsigned*)(Az + offA[r]),
                                             (AS3 unsigned*)(bb0 + r * 4096 + t * 16), 16, 0, 0);
#pragma unroll
        for (int r = 0; r < 4; ++r)
            __builtin_amdgcn_global_load_lds((const AS1 unsigned*)(Bz + offB[r]),
                                             (AS3 unsigned*)(bb0 + 16384 + r * 4096 + t * 16), 16, 0, 0);
    }
    __syncthreads();

    int cur = 0;
    for (int T = 0; T < NT; ++T) {
        char* bb  = lds8 + cur * 32768;
        char* bbn = lds8 + (cur ^ 1) * 32768;

        if (T + 1 < NT) {
            const long kcol = (long)(T + 1) << 6;
#pragma unroll
            for (int r = 0; r < 4; ++r)
                __builtin_amdgcn_global_load_lds((const AS1 unsigned*)(Az + offA[r] + kcol),
                                                 (AS3 unsigned*)(bbn + r * 4096 + t * 16), 16, 0, 0);
#pragma unroll
            for (int r = 0; r < 4; ++r)
                __builtin_amdgcn_global_load_lds((const AS1 unsigned*)(Bz + offB[r] + kcol),
                                                 (AS3 unsigned*)(bbn + 16384 + r * 4096 + t * 16), 16, 0, 0);
        }

        bf16x8 af[2][4], bfv[2][4];
#pragma unroll
        for (int ks = 0; ks < 2; ++ks)
#pragma unroll
            for (int m = 0; m < 4; ++m)
                af[ks][m] = *(const bf16x8*)(bb + aRow[m] + aCh[ks]);
#pragma unroll
        for (int ks = 0; ks < 2; ++ks)
#pragma unroll
            for (int n = 0; n < 4; ++n)
                bfv[ks][n] = *(const bf16x8*)(bb + bRow[n] + aCh[ks]);

        __builtin_amdgcn_s_setprio(1);
#pragma unroll
        for (int ks = 0; ks < 2; ++ks)
#pragma unroll
            for (int m = 0; m < 4; ++m)
#pragma unroll
                for (int n = 0; n < 4; ++n)
                    acc[m][n] = __builtin_amdgcn_mfma_f32_16x16x32_bf16(af[ks][m], bfv[ks][n], acc[m][n], 0, 0, 0);
        __builtin_amdgcn_s_setprio(0);

        __syncthreads();
        cur ^= 1;
    }

    const long crow = brow + wr * 64;
    const long ccol = bcol + wc * 64;
    const long cz = sCz * blockIdx.z;
#pragma unroll
    for (int m = 0; m < 4; ++m) {
#pragma unroll
        for (int n = 0; n < 4; ++n) {
#pragma unroll
            for (int j = 0; j < 4; ++j) {
                long r = crow + m * 16 + kq * 4 + j;
                long c = ccol + n * 16 + fr;
                float vv = acc[m][n][j];
                if (MODE == 0)      { vv += bias[c]; ((u16*)Cout)[cz + r * ldc + c] = f2bf(vv); }
                else if (MODE == 1) { vv += bias[r]; ((u16*)Cout)[cz + r * ldc + c] = f2bf(vv); }
                else if (MODE == 2) { ((_Float16*)Cout)[cz + r * ldc + c] = (_Float16)(vv * scale); }
                else                { ((float*)Cout)[cz + r * ldc + c] = vv; }
            }
        }
    }
}

// ---------------- row softmax: fp16 in -> bf16 out, in place, L=4096 ----------------
__global__ __launch_bounds__(256) void softmax_row(u16* __restrict__ S, int L) {
    const long row = blockIdx.x;
    u16* rp = S + row * L;
    const int t = threadIdx.x;
    const int lane = t & 63, wid = t >> 6;

    f16x8 h0 = *(const f16x8*)(rp + t * 16);
    f16x8 h1 = *(const f16x8*)(rp + t * 16 + 8);
    float x[16];
#pragma unroll
    for (int j = 0; j < 8; ++j) { x[j] = (float)h0[j]; x[8 + j] = (float)h1[j]; }

    float m = -1e30f;
#pragma unroll
    for (int j = 0; j < 16; ++j) m = fmaxf(m, x[j]);
#pragma unroll
    for (int o = 32; o; o >>= 1) m = fmaxf(m, __shfl_xor(m, o));

    __shared__ float redmax[4], redsum[4];
    if (lane == 0) redmax[wid] = m;
    __syncthreads();
    m = fmaxf(fmaxf(redmax[0], redmax[1]), fmaxf(redmax[2], redmax[3]));

    float e[16], s = 0.f;
#pragma unroll
    for (int j = 0; j < 16; ++j) { e[j] = __expf(x[j] - m); s += e[j]; }
#pragma unroll
    for (int o = 32; o; o >>= 1) s += __shfl_xor(s, o);
    if (lane == 0) redsum[wid] = s;
    __syncthreads();
    s = redsum[0] + redsum[1] + redsum[2] + redsum[3];
    float inv = 1.f / s;

    us8 o0, o1;
#pragma unroll
    for (int j = 0; j < 8; ++j) { o0[j] = f2bf(e[j] * inv); o1[j] = f2bf(e[8 + j] * inv); }
    *(us8*)(rp + t * 16) = o0;
    *(us8*)(rp + t * 16 + 8) = o1;
}

extern "C" void kernel_launch(void* const* d_in, const int* in_sizes, int n_in,
                              void* d_out, int out_size, void* d_ws, size_t ws_size,
                              hipStream_t stream) {
    (void)in_sizes; (void)n_in; (void)out_size;
    const float* q  = (const float*)d_in[0];
    const float* k  = (const float*)d_in[1];
    const float* v  = (const float*)d_in[2];
    const float* Wq = (const float*)d_in[3];
    const float* bq = (const float*)d_in[4];
    const float* Wk = (const float*)d_in[5];
    const float* bk = (const float*)d_in[6];
    const float* Wv = (const float*)d_in[7];
    const float* bv = (const float*)d_in[8];
    float* out = (float*)d_out;

    constexpr long MB = 1l << 20;
    char* ws = (char*)d_ws;
    u16* pq  = (u16*)(ws + 0 * MB);     // 32 MB  [16384,1024] bf16
    u16* pk  = (u16*)(ws + 32 * MB);    // 32 MB
    u16* pvT = (u16*)(ws + 64 * MB);    // 32 MB  [1024,16384] bf16 (pv transposed)
    u16* Wqb = (u16*)(ws + 96 * MB);    // 2 MB
    u16* Wkb = (u16*)(ws + 98 * MB);    // 2 MB
    u16* Wvb = (u16*)(ws + 100 * MB);   // 2 MB
    u16* qb  = (u16*)(ws + 104 * MB);   // 32 MB (dead after pq GEMM)
    u16* kb  = (u16*)(ws + 136 * MB);   // 32 MB (dead after pk GEMM)
    u16* vb  = (u16*)(ws + 168 * MB);   // 32 MB
    u16* S4  = (u16*)(ws + 104 * MB);   // z4: 128 MB (104..232), aliases qb/kb/vb (dead)

    const int L = 4096, E = 1024, NB = 4;
    const int n8_x = (NB * L * E) / 8;
    const int n8_w = (E * E) / 8;
    const bool z4 = ws_size >= (size_t)233 * MB;

    cvt3_f32_bf16<<<dim3(1024, 3), 256, 0, stream>>>(q, k, v, qb, kb, vb, n8_x);
    cvt3_f32_bf16<<<dim3(256, 3), 256, 0, stream>>>(Wq, Wk, Wv, Wqb, Wkb, Wvb, n8_w);

    // projections: pq = q@Wq^T + bq   (M=16384 -> gy=64, N=1024 -> gx=4) 256 blocks
    dim3 gproj(4, 64, 1);
    gemm256d<0><<<gproj, 512, 0, stream>>>(qb, Wqb, pq, bq, 1.f, E, E, E, E, 0, 0, 0);
    gemm256d<0><<<gproj, 512, 0, stream>>>(kb, Wkb, pk, bk, 1.f, E, E, E, E, 0, 0, 0);
    // pvT = Wv @ v^T + bv[row]   (M=1024 -> gy=4, N=16384 -> gx=64) 256 blocks
    dim3 gpv(64, 4, 1);
    gemm256d<1><<<gpv, 512, 0, stream>>>(Wvb, vb, pvT, bv, 1.f, E, E, E, NB * L, 0, 0, 0);

    const float scale = 0.03125f;  // 1/sqrt(1024)
    if (z4) {
        // S = pq @ pk^T * scale -> fp16, all 4 batches (16,16,4) = 1024 blocks
        gemm256d<2><<<dim3(16, 16, 4), 512, 0, stream>>>(pq, pk, (void*)S4,
                                                         nullptr, scale, E, E, E, L,
                                                         (long)L * E, (long)L * E, (long)L * L);
        softmax_row<<<NB * L, 256, 0, stream>>>(S4, L);
        // out = attn @ pvT^T   (4,16,4) = 256 blocks = 1/CU
        gemm256d<3><<<dim3(4, 16, 4), 512, 0, stream>>>(S4, pvT, out,
                                                        nullptr, 1.f, L, L, NB * L, E,
                                                        (long)L * L, (long)L, (long)L * E);
    } else {
        u16* S2 = S4;  // 64 MB, 2 batches
        for (int p = 0; p < 2; ++p) {
            const long zb = p * 2;
            gemm256d<2><<<dim3(16, 16, 2), 512, 0, stream>>>(pq + zb * L * E, pk + zb * L * E, (void*)S2,
                                                             nullptr, scale, E, E, E, L,
                                                             (long)L * E, (long)L * E, (long)L * L);
            softmax_row<<<2 * L, 256, 0, stream>>>(S2, L);
            gemm128<3><<<dim3(8, 32, 2), 256, 0, stream>>>(S2, pvT + zb * L, out + zb * L * E,
                                                           nullptr, 1.f, L, L, NB * L, E,
                                                           (long)L * L, (long)L, (long)L * E);
        }
    }
}